// Round 3
// baseline (84.093 us; speedup 1.0000x reference)
//
#include <hip/hip_runtime.h>
#include <cstddef>
#include <cstdint>

#define B_     2
#define FEA_   128
#define H_     480
#define W_     360
#define NH_    32
#define PT_    32
#define EMB_   3
#define NPTS_  120000
#define BN_EPS_ 1e-5f
#define HW_    (H_ * W_)

typedef float fx4 __attribute__((ext_vector_type(4)));

// ---------------------------------------------------------------------------
// Kernel 1: 1x1 conv restricted to the 32x32 (h,w) sub-block actually gathered.
// fea_sub[b][m][o], m = h*32 + w (h,w in [0,32)), o in [0,1024).
// Per-block tile: 64 pixels x 64 out-channels, K tiled by 64.
// As[k][px]: inner reads are broadcast float4 (free). Bs[ch][k] pad 65:
// reads (4S*tx mod 32 -> 8 banks, 2-way) and writes (k-contig) are free.
// ---------------------------------------------------------------------------
__global__ __launch_bounds__(256)
void conv_sub_gemm(const float* __restrict__ x, const float* __restrict__ conv_w,
                   const float* __restrict__ conv_b, float* __restrict__ fea_sub)
{
    __shared__ float As[64][64];   // [k][px]
    __shared__ float Bs[64][65];   // [ch][k], +1 pad
    const int b   = blockIdx.z;
    const int m0  = blockIdx.y * 64;     // pixel tile base
    const int o0  = blockIdx.x * 64;     // out-channel tile base
    const int tid = threadIdx.x;
    const int tx  = tid & 15;            // ch group (4 consecutive channels)
    const int ty  = tid >> 4;            // px group (4 consecutive pixels)
    const int h0  = m0 >> 5;             // tile spans rows h0, h0+1 (w 0..31)
    const float* xb = x + (size_t)b * FEA_ * HW_;
    float acc[4][4] = {};                // [px][ch]

    for (int k0 = 0; k0 < FEA_; k0 += 64) {
        // As[k][px] = x[b][k0+k][h0 + px/32][px%32]  (w-contiguous global reads)
        #pragma unroll
        for (int i = 0; i < 16; ++i) {
            int e  = tid + i * 256;
            int k  = e >> 6;
            int px = e & 63;
            As[k][px] = xb[(size_t)(k0 + k) * HW_ + (h0 + (px >> 5)) * W_ + (px & 31)];
        }
        // Bs[oo][k] = conv_w[o0+oo][k0+k]  (k-contiguous global reads)
        #pragma unroll
        for (int i = 0; i < 16; ++i) {
            int e  = tid + i * 256;
            int k  = e & 63;
            int oo = e >> 6;
            Bs[oo][k] = conv_w[(o0 + oo) * FEA_ + k0 + k];
        }
        __syncthreads();
        #pragma unroll 8
        for (int k = 0; k < 64; ++k) {
            const float4 av = *(const float4*)&As[k][ty * 4];  // broadcast, aligned
            float a[4] = {av.x, av.y, av.z, av.w};
            float bv[4];
            #pragma unroll
            for (int c = 0; c < 4; ++c) bv[c] = Bs[tx * 4 + c][k];
            #pragma unroll
            for (int i = 0; i < 4; ++i)
                #pragma unroll
                for (int j = 0; j < 4; ++j)
                    acc[i][j] += a[i] * bv[j];
        }
        __syncthreads();
    }
    // C write: 4 rows x float4, lanes tx contiguous -> 256B segments
    const float4 cb = *(const float4*)&conv_b[o0 + tx * 4];
    #pragma unroll
    for (int i = 0; i < 4; ++i) {
        const int m = m0 + ty * 4 + i;
        float4 v;
        v.x = acc[i][0] + cb.x; v.y = acc[i][1] + cb.y;
        v.z = acc[i][2] + cb.z; v.w = acc[i][3] + cb.w;
        *(float4*)&fea_sub[((size_t)b * 1024 + m) * 1024 + o0 + tx * 4] = v;
    }
}

// ---------------------------------------------------------------------------
// Kernel 2: per-point gather (128B contiguous) + MLP with LDS-staged,
// BN-folded weights. All weight reads are LDS broadcasts (ds_read_b128),
// never global — removes the per-thread global-latency chain.
// ---------------------------------------------------------------------------
__global__ __launch_bounds__(256)
void gather_mlp(const float* __restrict__ fea_sub, const int* __restrict__ grid_ind,
                const float* __restrict__ w1, const float* __restrict__ b1,
                const float* __restrict__ bn_gamma, const float* __restrict__ bn_beta,
                const float* __restrict__ bn_mean, const float* __restrict__ bn_var,
                const float* __restrict__ w2, const float* __restrict__ b2,
                float* __restrict__ out_off, float* __restrict__ out_fea)
{
    __shared__ __align__(16) float s_w1[PT_][PT_];  // BN-pre-scaled rows
    __shared__ float s_sc[PT_];
    __shared__ float s_shift[PT_];
    __shared__ __align__(16) float s_w2[EMB_][PT_];
    __shared__ float s_b2[EMB_];

    const int tid = threadIdx.x;
    if (tid < PT_) {
        const float sc = bn_gamma[tid] * rsqrtf(bn_var[tid] + BN_EPS_);
        s_sc[tid]    = sc;
        s_shift[tid] = (b1[tid] - bn_mean[tid]) * sc + bn_beta[tid];
    }
    __syncthreads();
    #pragma unroll
    for (int i = 0; i < 4; ++i) {
        const int e = tid + 256 * i;           // e < 1024
        s_w1[e >> 5][e & 31] = w1[e] * s_sc[e >> 5];
    }
    if (tid < EMB_ * PT_) s_w2[tid >> 5][tid & 31] = w2[tid];
    if (tid < EMB_)       s_b2[tid] = b2[tid];
    __syncthreads();

    const int p = blockIdx.x * 256 + tid;
    if (p >= B_ * NPTS_) return;
    const int b  = (p >= NPTS_) ? 1 : 0;
    const int gh = grid_ind[p * 3 + 0];
    const int gw = grid_ind[p * 3 + 1];
    const int gn = grid_ind[p * 3 + 2];

    const fx4* __restrict__ frow =
        (const fx4*)(fea_sub + (((size_t)b * 1024 + gh * 32 + gw) * 1024 + gn * 32));
    fx4 fv[8];
    #pragma unroll
    for (int i = 0; i < 8; ++i) fv[i] = frow[i];

    // pt_fea output (streamed, never re-read): nontemporal 16B stores
    fx4* __restrict__ orow = (fx4*)(out_fea + (size_t)p * PT_);
    #pragma unroll
    for (int i = 0; i < 8; ++i) __builtin_nontemporal_store(fv[i], &orow[i]);

    float fea[PT_];
    #pragma unroll
    for (int i = 0; i < 8; ++i) {
        fea[4 * i + 0] = fv[i].x; fea[4 * i + 1] = fv[i].y;
        fea[4 * i + 2] = fv[i].z; fea[4 * i + 3] = fv[i].w;
    }

    // h = relu(fea @ w1s^T + shift)   (BN + b1 folded into w1s/shift)
    float h[PT_];
    #pragma unroll
    for (int j = 0; j < PT_; ++j) {
        const float4* wr = (const float4*)&s_w1[j][0];  // uniform addr -> broadcast
        float a = s_shift[j];
        #pragma unroll
        for (int i = 0; i < 8; ++i) {
            const float4 wv = wr[i];
            a += wv.x * fea[4 * i + 0] + wv.y * fea[4 * i + 1]
               + wv.z * fea[4 * i + 2] + wv.w * fea[4 * i + 3];
        }
        h[j] = fmaxf(a, 0.0f);
    }
    // offsets = h @ w2^T + b2
    #pragma unroll
    for (int e = 0; e < EMB_; ++e) {
        const float4* wr = (const float4*)&s_w2[e][0];
        float a = s_b2[e];
        #pragma unroll
        for (int i = 0; i < 8; ++i) {
            const float4 wv = wr[i];
            a += wv.x * h[4 * i + 0] + wv.y * h[4 * i + 1]
               + wv.z * h[4 * i + 2] + wv.w * h[4 * i + 3];
        }
        out_off[(size_t)p * EMB_ + e] = a;
    }
}

// ---------------------------------------------------------------------------
// Fallback (only if ws_size < 8MB): fused per-point conv+MLP, 32 threads/point.
// ---------------------------------------------------------------------------
__global__ __launch_bounds__(256)
void fused_fallback(const float* __restrict__ x, const int* __restrict__ grid_ind,
                    const float* __restrict__ conv_w, const float* __restrict__ conv_b,
                    const float* __restrict__ w1, const float* __restrict__ b1,
                    const float* __restrict__ bn_gamma, const float* __restrict__ bn_beta,
                    const float* __restrict__ bn_mean, const float* __restrict__ bn_var,
                    const float* __restrict__ w2, const float* __restrict__ b2,
                    float* __restrict__ out_off, float* __restrict__ out_fea)
{
    __shared__ __align__(16) float s_x[8][FEA_];
    __shared__ float s_f[8][PT_ + 1];
    __shared__ float s_h[8][PT_ + 1];
    const int tid = threadIdx.x;
    const int lp  = tid >> 5;
    const int t   = tid & 31;
    const int p   = blockIdx.x * 8 + lp;

    const int b  = (p >= NPTS_) ? 1 : 0;
    const int gh = grid_ind[p * 3 + 0];
    const int gw = grid_ind[p * 3 + 1];
    const int gn = grid_ind[p * 3 + 2];

    const float* xb = x + (size_t)b * FEA_ * HW_ + gh * W_ + gw;
    #pragma unroll
    for (int i = 0; i < 4; ++i)
        s_x[lp][t + 32 * i] = xb[(size_t)(t + 32 * i) * HW_];
    __syncthreads();

    const int row = gn * PT_ + t;
    const float4* wr = (const float4*)(conv_w + row * FEA_);
    const float4* xv = (const float4*)s_x[lp];
    float a = 0.0f;
    #pragma unroll
    for (int i = 0; i < FEA_ / 4; ++i) {
        float4 wv = wr[i], xw = xv[i];
        a += wv.x * xw.x + wv.y * xw.y + wv.z * xw.z + wv.w * xw.w;
    }
    a += conv_b[row];
    s_f[lp][t] = a;
    out_fea[(size_t)p * PT_ + t] = a;
    __syncthreads();

    float hv = b1[t];
    #pragma unroll
    for (int j = 0; j < PT_; ++j) hv += s_f[lp][j] * w1[t * PT_ + j];
    const float sc = bn_gamma[t] * rsqrtf(bn_var[t] + BN_EPS_);
    hv = (hv - bn_mean[t]) * sc + bn_beta[t];
    s_h[lp][t] = fmaxf(hv, 0.0f);
    __syncthreads();

    if (t < EMB_) {
        float o = b2[t];
        #pragma unroll
        for (int j = 0; j < PT_; ++j) o += s_h[lp][j] * w2[t * PT_ + j];
        out_off[(size_t)p * EMB_ + t] = o;
    }
}

extern "C" void kernel_launch(void* const* d_in, const int* in_sizes, int n_in,
                              void* d_out, int out_size, void* d_ws, size_t ws_size,
                              hipStream_t stream)
{
    const float* x      = (const float*)d_in[0];
    const int*   gi     = (const int*)d_in[1];
    const float* conv_w = (const float*)d_in[2];
    const float* conv_b = (const float*)d_in[3];
    const float* w1     = (const float*)d_in[4];
    const float* b1     = (const float*)d_in[5];
    const float* bng    = (const float*)d_in[6];
    const float* bnb    = (const float*)d_in[7];
    const float* bnm    = (const float*)d_in[8];
    const float* bnv    = (const float*)d_in[9];
    const float* w2     = (const float*)d_in[10];
    const float* b2     = (const float*)d_in[11];

    float* out_off = (float*)d_out;                                  // [B,N,3]
    float* out_fea = out_off + (size_t)B_ * NPTS_ * EMB_;            // [B,N,32]

    const size_t fea_bytes = (size_t)B_ * 1024 * 1024 * sizeof(float);  // 8 MB
    if (ws_size >= fea_bytes) {
        float* fea_sub = (float*)d_ws;
        conv_sub_gemm<<<dim3(16, 16, 2), 256, 0, stream>>>(x, conv_w, conv_b, fea_sub);
        gather_mlp<<<dim3((B_ * NPTS_ + 255) / 256), 256, 0, stream>>>(
            fea_sub, gi, w1, b1, bng, bnb, bnm, bnv, w2, b2, out_off, out_fea);
    } else {
        fused_fallback<<<dim3(B_ * NPTS_ / 8), 256, 0, stream>>>(
            x, gi, conv_w, conv_b, w1, b1, bng, bnb, bnm, bnv, w2, b2, out_off, out_fea);
    }
}

// Round 4
// 47.716 us; speedup vs baseline: 1.7624x; 1.7624x over previous
//
#include <hip/hip_runtime.h>
#include <cstddef>
#include <cstdint>

#define B_     2
#define FEA_   128
#define H_     480
#define W_     360
#define NH_    32
#define PT_    32
#define EMB_   3
#define NPTS_  120000
#define BN_EPS_ 1e-5f
#define HW_    (H_ * W_)

typedef float fx4 __attribute__((ext_vector_type(4)));

// ---------------------------------------------------------------------------
// Kernel 1: 1x1 conv restricted to the 32x32 (h,w) sub-block actually gathered.
// fea_sub[b][m][o], m = h*32 + w (h,w in [0,32)), o in [0,1024).
// Block tile 64px x 64ch, FULL K=128 staged once (one barrier).
// As[k][px] (32KB), Bs[k][ch] pad 72 (36.9KB): inner loop is
// 2 x ds_read_b128 + 16 FMA per k. Bank math:
//   A read  As[k][4ty]: 4 addrs/wave, 16-lane broadcast        -> free
//   B read  Bs[k][4tx]: bank (72k+4tx)%32 -> 2-way             -> free
//   A write As[k][4pxq]: row-contig b128                       -> 2-way
//   B write Bs[4kq+i][ch]: bank (288kq+72i+ch)%32=(72i+ch)%32,
//           ch=lane&63 spans all banks                         -> 2-way
// ---------------------------------------------------------------------------
__global__ __launch_bounds__(256)
void conv_sub_gemm(const float* __restrict__ x, const float* __restrict__ conv_w,
                   const float* __restrict__ conv_b, float* __restrict__ fea_sub)
{
    __shared__ float As[FEA_][64];       // [k][px]
    __shared__ float Bs[FEA_][72];       // [k][ch], pad 72 (16B-aligned rows)
    const int b   = blockIdx.z;
    const int m0  = blockIdx.y * 64;     // pixel tile base
    const int o0  = blockIdx.x * 64;     // out-channel tile base
    const int tid = threadIdx.x;
    const int tx  = tid & 15;            // ch quad
    const int ty  = tid >> 4;            // px quad
    const int h0  = m0 >> 5;             // tile spans rows h0, h0+1 (w 0..31)
    const float* xb = x + (size_t)b * FEA_ * HW_;

    // Stage A: 2048 pixel-quads (128 k x 16 pxq), b128 global -> b128 LDS
    #pragma unroll
    for (int it = 0; it < 8; ++it) {
        const int e   = tid + it * 256;
        const int pxq = e & 15;
        const int k   = e >> 4;
        const int px  = pxq * 4;
        const fx4 v = *(const fx4*)&xb[(size_t)k * HW_ + (h0 + (px >> 5)) * W_ + (px & 31)];
        *(fx4*)&As[k][px] = v;
    }
    // Stage B (transpose): thread loads conv_w[o0+ch][4kq..4kq+3], writes column ch
    #pragma unroll
    for (int it = 0; it < 8; ++it) {
        const int e  = tid + it * 256;
        const int ch = e & 63;
        const int kq = e >> 6;           // 0..31
        const fx4 v = *(const fx4*)&conv_w[(size_t)(o0 + ch) * FEA_ + kq * 4];
        Bs[4 * kq + 0][ch] = v.x;
        Bs[4 * kq + 1][ch] = v.y;
        Bs[4 * kq + 2][ch] = v.z;
        Bs[4 * kq + 3][ch] = v.w;
    }
    __syncthreads();

    float acc[4][4] = {};                // [px][ch]
    #pragma unroll 8
    for (int k = 0; k < FEA_; ++k) {
        const fx4 av = *(const fx4*)&As[k][ty * 4];
        const fx4 bv = *(const fx4*)&Bs[k][tx * 4];
        #pragma unroll
        for (int i = 0; i < 4; ++i)
            #pragma unroll
            for (int j = 0; j < 4; ++j)
                acc[i][j] += av[i] * bv[j];
    }

    // C write: 4 rows x float4, lanes tx contiguous -> 256B segments
    const fx4 cb = *(const fx4*)&conv_b[o0 + tx * 4];
    #pragma unroll
    for (int i = 0; i < 4; ++i) {
        const int m = m0 + ty * 4 + i;
        fx4 v;
        v.x = acc[i][0] + cb.x; v.y = acc[i][1] + cb.y;
        v.z = acc[i][2] + cb.z; v.w = acc[i][3] + cb.w;
        *(fx4*)&fea_sub[((size_t)b * 1024 + m) * 1024 + o0 + tx * 4] = v;
    }
}

// ---------------------------------------------------------------------------
// Kernel 2: per-point gather (128B contiguous) + MLP. Weight/BN reads are
// wave-uniform addresses through uniform kernel-arg pointers with literal
// indices -> compiler scalarizes to s_load + SGPR-operand v_fmac (scalar
// pipe, zero VALU/LDS cost). Uniform control flow (clamp, predicated
// stores) so scalarization isn't blocked by divergence.
// ---------------------------------------------------------------------------
__global__ __launch_bounds__(256)
void gather_mlp(const float* __restrict__ fea_sub, const int* __restrict__ grid_ind,
                const float* __restrict__ w1, const float* __restrict__ b1,
                const float* __restrict__ bn_gamma, const float* __restrict__ bn_beta,
                const float* __restrict__ bn_mean, const float* __restrict__ bn_var,
                const float* __restrict__ w2, const float* __restrict__ b2,
                float* __restrict__ out_off, float* __restrict__ out_fea)
{
    const int p0     = blockIdx.x * 256 + threadIdx.x;
    const bool active = p0 < B_ * NPTS_;
    const int p      = active ? p0 : B_ * NPTS_ - 1;   // clamp: uniform flow
    const int b  = (p >= NPTS_) ? 1 : 0;
    const int gh = grid_ind[p * 3 + 0];
    const int gw = grid_ind[p * 3 + 1];
    const int gn = grid_ind[p * 3 + 2];

    const fx4* __restrict__ frow =
        (const fx4*)(fea_sub + (((size_t)b * 1024 + gh * 32 + gw) * 1024 + gn * 32));
    fx4 fv[8];
    #pragma unroll
    for (int i = 0; i < 8; ++i) fv[i] = frow[i];

    float fea[PT_];
    #pragma unroll
    for (int i = 0; i < 8; ++i) {
        fea[4 * i + 0] = fv[i].x; fea[4 * i + 1] = fv[i].y;
        fea[4 * i + 2] = fv[i].z; fea[4 * i + 3] = fv[i].w;
    }

    // pt_fea output (second tuple element), 128B contiguous per point
    if (active) {
        fx4* __restrict__ orow = (fx4*)(out_fea + (size_t)p * PT_);
        #pragma unroll
        for (int i = 0; i < 8; ++i) orow[i] = fv[i];
    }

    // h = relu(BN(fea @ w1^T + b1))  — weights via scalarized uniform loads
    float h[PT_];
    #pragma unroll
    for (int j = 0; j < PT_; ++j) {
        float a = b1[j];
        #pragma unroll
        for (int t = 0; t < PT_; ++t) a += fea[t] * w1[j * PT_ + t];
        const float sc = bn_gamma[j] * rsqrtf(bn_var[j] + BN_EPS_);
        a = (a - bn_mean[j]) * sc + bn_beta[j];
        h[j] = fmaxf(a, 0.0f);
    }
    // offsets = h @ w2^T + b2
    if (active) {
        #pragma unroll
        for (int e = 0; e < EMB_; ++e) {
            float a = b2[e];
            #pragma unroll
            for (int t = 0; t < PT_; ++t) a += h[t] * w2[e * PT_ + t];
            out_off[(size_t)p * EMB_ + e] = a;
        }
    }
}

// ---------------------------------------------------------------------------
// Fallback (only if ws_size < 8MB): fused per-point conv+MLP, 32 threads/point.
// ---------------------------------------------------------------------------
__global__ __launch_bounds__(256)
void fused_fallback(const float* __restrict__ x, const int* __restrict__ grid_ind,
                    const float* __restrict__ conv_w, const float* __restrict__ conv_b,
                    const float* __restrict__ w1, const float* __restrict__ b1,
                    const float* __restrict__ bn_gamma, const float* __restrict__ bn_beta,
                    const float* __restrict__ bn_mean, const float* __restrict__ bn_var,
                    const float* __restrict__ w2, const float* __restrict__ b2,
                    float* __restrict__ out_off, float* __restrict__ out_fea)
{
    __shared__ __align__(16) float s_x[8][FEA_];
    __shared__ float s_f[8][PT_ + 1];
    __shared__ float s_h[8][PT_ + 1];
    const int tid = threadIdx.x;
    const int lp  = tid >> 5;
    const int t   = tid & 31;
    const int p   = blockIdx.x * 8 + lp;

    const int b  = (p >= NPTS_) ? 1 : 0;
    const int gh = grid_ind[p * 3 + 0];
    const int gw = grid_ind[p * 3 + 1];
    const int gn = grid_ind[p * 3 + 2];

    const float* xb = x + (size_t)b * FEA_ * HW_ + gh * W_ + gw;
    #pragma unroll
    for (int i = 0; i < 4; ++i)
        s_x[lp][t + 32 * i] = xb[(size_t)(t + 32 * i) * HW_];
    __syncthreads();

    const int row = gn * PT_ + t;
    const float4* wr = (const float4*)(conv_w + row * FEA_);
    const float4* xv = (const float4*)s_x[lp];
    float a = 0.0f;
    #pragma unroll
    for (int i = 0; i < FEA_ / 4; ++i) {
        float4 wv = wr[i], xw = xv[i];
        a += wv.x * xw.x + wv.y * xw.y + wv.z * xw.z + wv.w * xw.w;
    }
    a += conv_b[row];
    s_f[lp][t] = a;
    out_fea[(size_t)p * PT_ + t] = a;
    __syncthreads();

    float hv = b1[t];
    #pragma unroll
    for (int j = 0; j < PT_; ++j) hv += s_f[lp][j] * w1[t * PT_ + j];
    const float sc = bn_gamma[t] * rsqrtf(bn_var[t] + BN_EPS_);
    hv = (hv - bn_mean[t]) * sc + bn_beta[t];
    s_h[lp][t] = fmaxf(hv, 0.0f);
    __syncthreads();

    if (t < EMB_) {
        float o = b2[t];
        #pragma unroll
        for (int j = 0; j < PT_; ++j) o += s_h[lp][j] * w2[t * PT_ + j];
        out_off[(size_t)p * EMB_ + t] = o;
    }
}

extern "C" void kernel_launch(void* const* d_in, const int* in_sizes, int n_in,
                              void* d_out, int out_size, void* d_ws, size_t ws_size,
                              hipStream_t stream)
{
    const float* x      = (const float*)d_in[0];
    const int*   gi     = (const int*)d_in[1];
    const float* conv_w = (const float*)d_in[2];
    const float* conv_b = (const float*)d_in[3];
    const float* w1     = (const float*)d_in[4];
    const float* b1     = (const float*)d_in[5];
    const float* bng    = (const float*)d_in[6];
    const float* bnb    = (const float*)d_in[7];
    const float* bnm    = (const float*)d_in[8];
    const float* bnv    = (const float*)d_in[9];
    const float* w2     = (const float*)d_in[10];
    const float* b2     = (const float*)d_in[11];

    float* out_off = (float*)d_out;                                  // [B,N,3]
    float* out_fea = out_off + (size_t)B_ * NPTS_ * EMB_;            // [B,N,32]

    const size_t fea_bytes = (size_t)B_ * 1024 * 1024 * sizeof(float);  // 8 MB
    if (ws_size >= fea_bytes) {
        float* fea_sub = (float*)d_ws;
        conv_sub_gemm<<<dim3(16, 16, 2), 256, 0, stream>>>(x, conv_w, conv_b, fea_sub);
        gather_mlp<<<dim3((B_ * NPTS_ + 255) / 256), 256, 0, stream>>>(
            fea_sub, gi, w1, b1, bng, bnb, bnm, bnv, w2, b2, out_off, out_fea);
    } else {
        fused_fallback<<<dim3(B_ * NPTS_ / 8), 256, 0, stream>>>(
            x, gi, conv_w, conv_b, w1, b1, bng, bnb, bnm, bnv, w2, b2, out_off, out_fea);
    }
}